// Round 1
// baseline (281.060 us; speedup 1.0000x reference)
//
#include <hip/hip_runtime.h>
#include <hip/hip_bf16.h>
#include <cstdint>
#include <cstddef>

namespace {

constexpr int BATCH = 16;
constexpr int LEN   = 8192;
constexpr int CIN   = 257;
constexpr int CS    = 256;   // space channels
constexpr int NF    = 4096;  // output frames
constexpr int LPAD  = LEN + 4;   // 8196 padded rows per batch (2 each side)
constexpr int KG    = 1280;      // GEMM K (5 taps * 256 ch), time handled as rank-1
constexpr int MT    = 64;        // frames per block

// workspace layout
constexpr size_t XS_ELEMS  = (size_t)BATCH * LPAD * CS;    // bf16 padded input
constexpr size_t XS_BYTES  = XS_ELEMS * 2;                  // 67,141,632
constexpr size_t RSQ_OFF   = XS_BYTES;
constexpr size_t RSQ_BYTES = (size_t)BATCH * LPAD * 4;      // per-row sumsq (f32)
constexpr size_t WT_OFF    = RSQ_OFF + RSQ_BYTES;
constexpr size_t WT_BYTES  = (size_t)CS * KG * 2;           // bf16 W[1:,1:]
constexpr size_t W0_OFF    = WT_OFF + WT_BYTES;
constexpr size_t WS_NEED   = W0_OFF + (size_t)CS * 4;       // ~68.3 MB

typedef __attribute__((ext_vector_type(8))) short short8;
typedef __attribute__((ext_vector_type(4))) float f32x4;

__device__ __forceinline__ unsigned short f2bf_bits(float f) {
  union { __hip_bfloat16 h; unsigned short u; } cv;
  cv.h = __float2bfloat16(f);
  return cv.u;
}

__device__ __forceinline__ void async_cp16(const void* g, void* l) {
  __builtin_amdgcn_global_load_lds(
      (const __attribute__((address_space(1))) void*)g,
      (__attribute__((address_space(3))) void*)l,
      16, 0, 0);
}

} // namespace

// ---------------- prep 1: W (257x1281 f32) -> Wt bf16 [256][1280] + w0[256] f32
__global__ void prep_w_kernel(const float* __restrict__ W,
                              __hip_bfloat16* __restrict__ wt,
                              float* __restrict__ w0) {
  int n = blockIdx.x;                    // 0..255  -> out channel n+1
  const float* wrow = W + (size_t)(n + 1) * 1281;
  for (int k = threadIdx.x; k < KG; k += blockDim.x)
    wt[(size_t)n * KG + k] = __float2bfloat16(wrow[1 + k]);
  if (threadIdx.x == 0) w0[n] = wrow[0];
}

// ---------------- prep 2: x f32 -> xs bf16 (padded rows) + rowsq f32
__global__ void prep_x_kernel(const float* __restrict__ x,
                              __hip_bfloat16* __restrict__ xs,
                              float* __restrict__ rowsq) {
  const int tid = threadIdx.x;
  const int bx  = blockIdx.x;
  if (bx < (BATCH * LEN) / 4) {
    int r    = bx * 4 + (tid >> 6);      // global real row 0..131071
    int lane = tid & 63;
    int b    = r >> 13;
    int t    = r & (LEN - 1);
    size_t tpg = (size_t)b * LPAD + 2 + t;
    const float* src = x + (size_t)r * CIN + 1 + lane * 4;
    float f0 = src[0], f1 = src[1], f2 = src[2], f3 = src[3];
    float s = f0 * f0 + f1 * f1 + f2 * f2 + f3 * f3;
    ushort4 pk;
    pk.x = f2bf_bits(f0); pk.y = f2bf_bits(f1);
    pk.z = f2bf_bits(f2); pk.w = f2bf_bits(f3);
    *(ushort4*)(xs + tpg * CS + lane * 4) = pk;
    for (int off = 32; off > 0; off >>= 1) s += __shfl_down(s, off);
    if (lane == 0) rowsq[tpg] = s;
  } else {
    // zero the 64 pad rows (4 per batch) + their rowsq
    for (int i = tid; i < 64 * 128; i += 256) {
      int row = i >> 7, u = i & 127;
      int b = row >> 2, j = row & 3;
      size_t tpg = (size_t)b * LPAD + (j < 2 ? j : 8192 + j);  // 0,1,8194,8195
      ((uint32_t*)xs)[tpg * 128 + u] = 0;   // 256 bf16 = 128 dwords per row
      if (u == 0) rowsq[tpg] = 0.0f;
    }
  }
}

// ---------------- main GEMM: [64 frames] x [256 out ch], K=1280, bf16 MFMA
// block: 256 threads = 4 waves, each wave 64x64 (4x4 tiles of 16x16x32)
__global__ __launch_bounds__(256, 3) void lorentz_gemm_kernel(
    const __hip_bfloat16* __restrict__ xs,
    const __hip_bfloat16* __restrict__ wt,
    const float* __restrict__ rowsq,
    const float* __restrict__ w0,
    const float* __restrict__ bvec,
    float* __restrict__ out) {
  // LDS: A tile 64x64 bf16 (8KB) + B tile 256x64 bf16 (32KB), chunk-XOR-swizzled
  __shared__ alignas(16) char lds[8192 + 32768];
  __shared__ alignas(16) float time0_s[64];
  __shared__ alignas(16) float normsq_s[64];
  char* A_lds = lds;
  char* B_lds = lds + 8192;

  const int tid   = threadIdx.x;
  const int w     = tid >> 6;        // wave id = n-slice
  const int lane  = tid & 63;
  const int row16 = lane & 15;
  const int q     = lane >> 4;

  const int bx    = blockIdx.x;
  const int b     = bx >> 6;
  const int Mbase = (bx & 63) * MT;

  const __hip_bfloat16* xsb = xs + ((size_t)b * LPAD + 2 * Mbase) * CS;

  f32x4 acc[4][4];
#pragma unroll
  for (int i = 0; i < 4; ++i)
#pragma unroll
    for (int j = 0; j < 4; ++j) acc[i][j] = (f32x4){0.f, 0.f, 0.f, 0.f};

  const int csw = (lane & 7) ^ (lane >> 3);  // staging source chunk (lane-const)

  for (int it = 0; it < 20; ++it) {
    const int kk = it >> 2;
    const int c0 = (it & 3) << 6;
    const int k0 = it << 6;
    __syncthreads();  // previous iteration's compute done before overwrite
    // stage A: 512 chunks of 16B, 2 wave-issues per wave
#pragma unroll
    for (int j = 0; j < 2; ++j) {
      int m = w * 16 + j * 8 + (lane >> 3);
      const void* g = xsb + (size_t)(2 * m + kk) * CS + c0 + csw * 8;
      async_cp16(g, A_lds + (w * 2 + j) * 1024);
    }
    // stage B: 2048 chunks, 8 wave-issues per wave
#pragma unroll
    for (int j = 0; j < 8; ++j) {
      int n = w * 64 + j * 8 + (lane >> 3);
      const void* g = wt + (size_t)n * KG + k0 + csw * 8;
      async_cp16(g, B_lds + (w * 8 + j) * 1024);
    }
    __syncthreads();  // loads landed (compiler emits vmcnt(0) before barrier)
#pragma unroll
    for (int s = 0; s < 2; ++s) {
      const int p = (s * 4 + q) ^ (lane & 7);  // swizzled chunk position
      short8 af[4], bf[4];
#pragma unroll
      for (int mt = 0; mt < 4; ++mt)
        af[mt] = *(const short8*)(A_lds + ((mt * 16 + row16) * 8 + p) * 16);
#pragma unroll
      for (int nt = 0; nt < 4; ++nt)
        bf[nt] = *(const short8*)(B_lds + ((w * 64 + nt * 16 + row16) * 8 + p) * 16);
#pragma unroll
      for (int mt = 0; mt < 4; ++mt)
#pragma unroll
        for (int nt = 0; nt < 4; ++nt)
          acc[mt][nt] = __builtin_amdgcn_mfma_f32_16x16x32_bf16(
              af[mt], bf[nt], acc[mt][nt], 0, 0, 0);
    }
  }

  // epilogue: time0 (rank-1) + bias, renorm across 256 channels, store
  if (tid < 64) {
    const float* rs = rowsq + (size_t)b * LPAD + 2 * (Mbase + tid);
    float s5 = rs[0] + rs[1] + rs[2] + rs[3] + rs[4];
    time0_s[tid] = sqrtf(1.0f + s5);
    normsq_s[tid] = 0.0f;
  }
  __syncthreads();

  float w0v[4], bv[4];
#pragma unroll
  for (int nt = 0; nt < 4; ++nt) {
    int n = w * 64 + nt * 16 + row16;
    w0v[nt] = w0[n];
    bv[nt]  = bvec[1 + n];
  }

#pragma unroll
  for (int mt = 0; mt < 4; ++mt) {
    f32x4 t4 = *(const f32x4*)&time0_s[mt * 16 + q * 4];
#pragma unroll
    for (int nt = 0; nt < 4; ++nt)
#pragma unroll
      for (int r = 0; r < 4; ++r)
        acc[mt][nt][r] = acc[mt][nt][r] + t4[r] * w0v[nt] + bv[nt];
#pragma unroll
    for (int r = 0; r < 4; ++r) {
      float ps = 0.f;
#pragma unroll
      for (int nt = 0; nt < 4; ++nt) ps += acc[mt][nt][r] * acc[mt][nt][r];
      ps += __shfl_xor(ps, 1);
      ps += __shfl_xor(ps, 2);
      ps += __shfl_xor(ps, 4);
      ps += __shfl_xor(ps, 8);
      if (row16 == 0) atomicAdd(&normsq_s[mt * 16 + q * 4 + r], ps);
    }
  }
  __syncthreads();

#pragma unroll
  for (int mt = 0; mt < 4; ++mt) {
#pragma unroll
    for (int r = 0; r < 4; ++r) {
      int m = mt * 16 + q * 4 + r;
      float nsq  = normsq_s[m];
      float norm = sqrtf(nsq);
      float scale = fminf(1.0f, 1000.0f / fmaxf(norm, 1e-8f));
      size_t ob = ((size_t)b * NF + Mbase + m) * 257;
#pragma unroll
      for (int nt = 0; nt < 4; ++nt) {
        int n = w * 64 + nt * 16 + row16;
        out[ob + 1 + n] = acc[mt][nt][r] * scale;
      }
    }
  }
  if (tid < 64) {
    float nsq  = normsq_s[tid];
    float norm = sqrtf(nsq);
    float scale = fminf(1.0f, 1000.0f / fmaxf(norm, 1e-8f));
    size_t ob = ((size_t)b * NF + Mbase + tid) * 257;
    out[ob] = sqrtf(1.0f + scale * scale * nsq);
  }
}

// ---------------- safety fallback (only if ws too small): naive fp32
__global__ void fallback_kernel(const float* __restrict__ x,
                                const float* __restrict__ W,
                                const float* __restrict__ bvec,
                                float* __restrict__ out) {
  int fid = blockIdx.x;
  int b = fid >> 12;
  int g = fid & (NF - 1);
  __shared__ float patch[1280];
  __shared__ float red[256];
  int tid = threadIdx.x;
  float ss = 0.f;
  for (int k = tid; k < 1280; k += 256) {
    int kk = k >> 8, c = k & 255;
    int t = 2 * g + kk - 2;
    float v = (t >= 0 && t < LEN) ? x[((size_t)b * LEN + t) * CIN + 1 + c] : 0.f;
    patch[k] = v;
    ss += v * v;
  }
  red[tid] = ss;
  __syncthreads();
  for (int off = 128; off > 0; off >>= 1) {
    if (tid < off) red[tid] += red[tid + off];
    __syncthreads();
  }
  float time0 = sqrtf(1.f + red[0]);
  __syncthreads();
  const float* wrow = W + (size_t)(tid + 1) * 1281;
  float acc = time0 * wrow[0] + bvec[tid + 1];
  for (int k = 0; k < 1280; ++k) acc += wrow[1 + k] * patch[k];
  red[tid] = acc * acc;
  __syncthreads();
  for (int off = 128; off > 0; off >>= 1) {
    if (tid < off) red[tid] += red[tid + off];
    __syncthreads();
  }
  float nsq = red[0];
  float norm = sqrtf(nsq);
  float scale = fminf(1.f, 1000.f / fmaxf(norm, 1e-8f));
  size_t ob = ((size_t)b * NF + g) * 257;
  out[ob + 1 + tid] = acc * scale;
  if (tid == 0) out[ob] = sqrtf(1.f + scale * scale * nsq);
}

extern "C" void kernel_launch(void* const* d_in, const int* in_sizes, int n_in,
                              void* d_out, int out_size, void* d_ws, size_t ws_size,
                              hipStream_t stream) {
  const float* x  = (const float*)d_in[0];
  const float* W  = (const float*)d_in[1];
  const float* bv = (const float*)d_in[2];
  float* out = (float*)d_out;

  if (ws_size >= WS_NEED) {
    char* ws = (char*)d_ws;
    __hip_bfloat16* xs = (__hip_bfloat16*)ws;
    float* rowsq       = (float*)(ws + RSQ_OFF);
    __hip_bfloat16* wt = (__hip_bfloat16*)(ws + WT_OFF);
    float* w0          = (float*)(ws + W0_OFF);
    prep_w_kernel<<<256, 256, 0, stream>>>(W, wt, w0);
    prep_x_kernel<<<(BATCH * LEN) / 4 + 1, 256, 0, stream>>>(x, xs, rowsq);
    lorentz_gemm_kernel<<<BATCH * (NF / MT), 256, 0, stream>>>(xs, wt, rowsq, w0, bv, out);
  } else {
    fallback_kernel<<<BATCH * NF, 256, 0, stream>>>(x, W, bv, out);
  }
}

// Round 2
// 272.331 us; speedup vs baseline: 1.0321x; 1.0321x over previous
//
#include <hip/hip_runtime.h>
#include <hip/hip_bf16.h>
#include <cstdint>
#include <cstddef>

namespace {

constexpr int BATCH = 16;
constexpr int LEN   = 8192;
constexpr int CIN   = 257;
constexpr int CS    = 256;   // space channels
constexpr int NF    = 4096;  // output frames
constexpr int LPAD  = LEN + 4;   // 8196 padded rows per batch (2 each side)
constexpr int KG    = 1280;      // GEMM K (5 taps * 256 ch), time handled as rank-1
constexpr int MT    = 128;       // frames per block

// workspace layout
constexpr size_t XS_ELEMS  = (size_t)BATCH * LPAD * CS;    // bf16 padded input
constexpr size_t XS_BYTES  = XS_ELEMS * 2;                  // 67,141,632
constexpr size_t RSQ_OFF   = XS_BYTES;
constexpr size_t RSQ_BYTES = (size_t)BATCH * LPAD * 4;      // per-row sumsq (f32)
constexpr size_t WT_OFF    = RSQ_OFF + RSQ_BYTES;
constexpr size_t WT_BYTES  = (size_t)CS * KG * 2;           // bf16 W[1:,1:]
constexpr size_t W0_OFF    = WT_OFF + WT_BYTES;
constexpr size_t WS_NEED   = W0_OFF + (size_t)CS * 4;       // ~68.3 MB

typedef __attribute__((ext_vector_type(8))) short short8;
typedef __attribute__((ext_vector_type(8))) unsigned short ushort8v;
typedef __attribute__((ext_vector_type(4))) float f32x4;

__device__ __forceinline__ unsigned short f2bf_bits(float f) {
  union { __hip_bfloat16 h; unsigned short u; } cv;
  cv.h = __float2bfloat16(f);
  return cv.u;
}

__device__ __forceinline__ void async_cp16(const void* g, void* l) {
  __builtin_amdgcn_global_load_lds(
      (const __attribute__((address_space(1))) void*)g,
      (__attribute__((address_space(3))) void*)l,
      16, 0, 0);
}

} // namespace

// ---------------- prep 1: W (257x1281 f32) -> Wt bf16 [256][1280] + w0[256] f32
__global__ void prep_w_kernel(const float* __restrict__ W,
                              __hip_bfloat16* __restrict__ wt,
                              float* __restrict__ w0) {
  int n = blockIdx.x;                    // 0..255  -> out channel n+1
  const float* wrow = W + (size_t)(n + 1) * 1281;
  for (int k = threadIdx.x; k < KG; k += blockDim.x)
    wt[(size_t)n * KG + k] = __float2bfloat16(wrow[1 + k]);
  if (threadIdx.x == 0) w0[n] = wrow[0];
}

// ---------------- prep 2: x f32 -> xs bf16 (padded rows) + rowsq f32
// block = 256 threads handles 16 rows = 4112 floats = 16448 B (16B aligned).
__global__ void prep_x_kernel(const float* __restrict__ x,
                              __hip_bfloat16* __restrict__ xs,
                              float* __restrict__ rowsq) {
  const int tid = threadIdx.x;
  const int bx  = blockIdx.x;
  if (bx < 8192) {
    __shared__ float4 xf4[1028];
    const float4* src = (const float4*)(x + (size_t)bx * 4112);
#pragma unroll
    for (int i = 0; i < 4; ++i) {
      int idx = i * 256 + tid;
      xf4[idx] = src[idx];
    }
    if (tid < 4) xf4[1024 + tid] = src[1024 + tid];
    __syncthreads();
    const float* xf = (const float*)xf4;
    const int row = tid >> 4, seg = tid & 15;
    const float* v = xf + row * 257 + 1 + seg * 16;
    float ss = 0.f;
    unsigned short u[16];
#pragma unroll
    for (int i = 0; i < 16; ++i) {
      float f = v[i];
      ss += f * f;
      u[i] = f2bf_bits(f);
    }
    const int b = bx >> 9;
    const int t = (bx & 511) * 16 + row;
    const size_t tpg = (size_t)b * LPAD + 2 + t;
    ushort8v* dst = (ushort8v*)((unsigned short*)xs + tpg * CS + seg * 16);
    ushort8v p0, p1;
#pragma unroll
    for (int i = 0; i < 8; ++i) { p0[i] = u[i]; p1[i] = u[8 + i]; }
    dst[0] = p0;
    dst[1] = p1;
    ss += __shfl_xor(ss, 1);
    ss += __shfl_xor(ss, 2);
    ss += __shfl_xor(ss, 4);
    ss += __shfl_xor(ss, 8);
    if (seg == 0) rowsq[tpg] = ss;
  } else {
    // zero the 64 pad rows (4 per batch) + their rowsq
    for (int i = tid; i < 64 * 128; i += 256) {
      int row = i >> 7, uo = i & 127;
      int b = row >> 2, j = row & 3;
      size_t tpg = (size_t)b * LPAD + (j < 2 ? j : 8192 + j);  // 0,1,8194,8195
      ((uint32_t*)xs)[tpg * 128 + uo] = 0;   // 256 bf16 = 128 dwords per row
      if (uo == 0) rowsq[tpg] = 0.0f;
    }
  }
}

// ---------------- main GEMM: [128 frames] x [256 out ch], K=1280, bf16 MFMA
// block: 512 threads = 8 waves; wave (mh = w>>2, nq = w&3) computes 64x64
__global__ __launch_bounds__(512, 4) void lorentz_gemm_kernel(
    const __hip_bfloat16* __restrict__ xs,
    const __hip_bfloat16* __restrict__ wt,
    const float* __restrict__ rowsq,
    const float* __restrict__ w0,
    const float* __restrict__ bvec,
    float* __restrict__ out) {
  // LDS: A tile 128x64 bf16 (16KB) + B tile 256x64 bf16 (32KB), chunk-XOR-swizzled
  __shared__ alignas(16) char lds[16384 + 32768];
  __shared__ alignas(16) float time0_s[128];
  __shared__ alignas(16) float normsq_s[128];
  char* A_lds = lds;
  char* B_lds = lds + 16384;

  const int tid   = threadIdx.x;
  const int w     = tid >> 6;
  const int lane  = tid & 63;
  const int row16 = lane & 15;
  const int q     = lane >> 4;
  const int mh    = w >> 2;     // 0..1  M-half
  const int nq    = w & 3;      // 0..3  N-quarter

  const int bx    = blockIdx.x;
  const int b     = bx >> 5;
  const int Mblk  = (bx & 31) * MT;

  const __hip_bfloat16* xsb = xs + ((size_t)b * LPAD + 2 * Mblk) * CS;

  f32x4 acc[4][4];
#pragma unroll
  for (int i = 0; i < 4; ++i)
#pragma unroll
    for (int j = 0; j < 4; ++j) acc[i][j] = (f32x4){0.f, 0.f, 0.f, 0.f};

  const int csw = (lane & 7) ^ (lane >> 3);  // staging source chunk (lane-const)

  for (int it = 0; it < 20; ++it) {
    const int kk = it >> 2;
    const int c0 = (it & 3) << 6;
    const int k0 = it << 6;
    __syncthreads();  // previous iteration's compute done before overwrite
    // stage A: 128 rows x 8 chunks = 1024 chunks, 2 wave-issues per wave
#pragma unroll
    for (int j = 0; j < 2; ++j) {
      int m = w * 16 + j * 8 + (lane >> 3);
      const void* g = xsb + (size_t)(2 * m + kk) * CS + c0 + csw * 8;
      async_cp16(g, A_lds + (w * 2 + j) * 1024);
    }
    // stage B: 256 rows x 8 chunks = 2048 chunks, 4 wave-issues per wave
#pragma unroll
    for (int j = 0; j < 4; ++j) {
      int n = w * 32 + j * 8 + (lane >> 3);
      const void* g = wt + (size_t)n * KG + k0 + csw * 8;
      async_cp16(g, B_lds + (w * 4 + j) * 1024);
    }
    __syncthreads();  // loads landed (compiler emits vmcnt(0) before barrier)
#pragma unroll
    for (int s = 0; s < 2; ++s) {
      const int p = (s * 4 + q) ^ (lane & 7);  // swizzled chunk position
      short8 bfr[4];
#pragma unroll
      for (int nt = 0; nt < 4; ++nt)
        bfr[nt] = *(const short8*)(B_lds + ((nq * 64 + nt * 16 + row16) * 8 + p) * 16);
#pragma unroll
      for (int mt = 0; mt < 4; ++mt) {
        short8 af = *(const short8*)(A_lds + ((mh * 64 + mt * 16 + row16) * 8 + p) * 16);
#pragma unroll
        for (int nt = 0; nt < 4; ++nt)
          acc[mt][nt] = __builtin_amdgcn_mfma_f32_16x16x32_bf16(
              af, bfr[nt], acc[mt][nt], 0, 0, 0);
      }
    }
  }

  // epilogue: time0 (rank-1) + bias, renorm across 256 channels, store
  __syncthreads();
  if (tid < 128) {
    const float* rs = rowsq + (size_t)b * LPAD + 2 * (Mblk + tid);
    float s5 = rs[0] + rs[1] + rs[2] + rs[3] + rs[4];
    time0_s[tid] = sqrtf(1.0f + s5);
    normsq_s[tid] = 0.0f;
  }
  __syncthreads();

  float w0v[4], bv[4];
#pragma unroll
  for (int nt = 0; nt < 4; ++nt) {
    int n = nq * 64 + nt * 16 + row16;
    w0v[nt] = w0[n];
    bv[nt]  = bvec[1 + n];
  }

#pragma unroll
  for (int mt = 0; mt < 4; ++mt) {
    f32x4 t4 = *(const f32x4*)&time0_s[mh * 64 + mt * 16 + q * 4];
#pragma unroll
    for (int nt = 0; nt < 4; ++nt)
#pragma unroll
      for (int r = 0; r < 4; ++r)
        acc[mt][nt][r] = acc[mt][nt][r] + t4[r] * w0v[nt] + bv[nt];
#pragma unroll
    for (int r = 0; r < 4; ++r) {
      float ps = 0.f;
#pragma unroll
      for (int nt = 0; nt < 4; ++nt) ps += acc[mt][nt][r] * acc[mt][nt][r];
      ps += __shfl_xor(ps, 1);
      ps += __shfl_xor(ps, 2);
      ps += __shfl_xor(ps, 4);
      ps += __shfl_xor(ps, 8);
      if (row16 == 0) atomicAdd(&normsq_s[mh * 64 + mt * 16 + q * 4 + r], ps);
    }
  }
  __syncthreads();

#pragma unroll
  for (int mt = 0; mt < 4; ++mt) {
#pragma unroll
    for (int r = 0; r < 4; ++r) {
      int m = mh * 64 + mt * 16 + q * 4 + r;
      float nsq  = normsq_s[m];
      float norm = sqrtf(nsq);
      float scale = fminf(1.0f, 1000.0f / fmaxf(norm, 1e-8f));
      size_t ob = ((size_t)b * NF + Mblk + m) * 257;
#pragma unroll
      for (int nt = 0; nt < 4; ++nt) {
        int n = nq * 64 + nt * 16 + row16;
        out[ob + 1 + n] = acc[mt][nt][r] * scale;
      }
    }
  }
  if (tid < 128) {
    float nsq  = normsq_s[tid];
    float norm = sqrtf(nsq);
    float scale = fminf(1.0f, 1000.0f / fmaxf(norm, 1e-8f));
    size_t ob = ((size_t)b * NF + Mblk + tid) * 257;
    out[ob] = sqrtf(1.0f + scale * scale * nsq);
  }
}

// ---------------- safety fallback (only if ws too small): naive fp32
__global__ void fallback_kernel(const float* __restrict__ x,
                                const float* __restrict__ W,
                                const float* __restrict__ bvec,
                                float* __restrict__ out) {
  int fid = blockIdx.x;
  int b = fid >> 12;
  int g = fid & (NF - 1);
  __shared__ float patch[1280];
  __shared__ float red[256];
  int tid = threadIdx.x;
  float ss = 0.f;
  for (int k = tid; k < 1280; k += 256) {
    int kk = k >> 8, c = k & 255;
    int t = 2 * g + kk - 2;
    float v = (t >= 0 && t < LEN) ? x[((size_t)b * LEN + t) * CIN + 1 + c] : 0.f;
    patch[k] = v;
    ss += v * v;
  }
  red[tid] = ss;
  __syncthreads();
  for (int off = 128; off > 0; off >>= 1) {
    if (tid < off) red[tid] += red[tid + off];
    __syncthreads();
  }
  float time0 = sqrtf(1.f + red[0]);
  __syncthreads();
  const float* wrow = W + (size_t)(tid + 1) * 1281;
  float acc = time0 * wrow[0] + bvec[tid + 1];
  for (int k = 0; k < 1280; ++k) acc += wrow[1 + k] * patch[k];
  red[tid] = acc * acc;
  __syncthreads();
  for (int off = 128; off > 0; off >>= 1) {
    if (tid < off) red[tid] += red[tid + off];
    __syncthreads();
  }
  float nsq = red[0];
  float norm = sqrtf(nsq);
  float scale = fminf(1.f, 1000.f / fmaxf(norm, 1e-8f));
  size_t ob = ((size_t)b * NF + g) * 257;
  out[ob + 1 + tid] = acc * scale;
  if (tid == 0) out[ob] = sqrtf(1.f + scale * scale * nsq);
}

extern "C" void kernel_launch(void* const* d_in, const int* in_sizes, int n_in,
                              void* d_out, int out_size, void* d_ws, size_t ws_size,
                              hipStream_t stream) {
  const float* x  = (const float*)d_in[0];
  const float* W  = (const float*)d_in[1];
  const float* bv = (const float*)d_in[2];
  float* out = (float*)d_out;

  if (ws_size >= WS_NEED) {
    char* ws = (char*)d_ws;
    __hip_bfloat16* xs = (__hip_bfloat16*)ws;
    float* rowsq       = (float*)(ws + RSQ_OFF);
    __hip_bfloat16* wt = (__hip_bfloat16*)(ws + WT_OFF);
    float* w0          = (float*)(ws + W0_OFF);
    prep_w_kernel<<<256, 256, 0, stream>>>(W, wt, w0);
    prep_x_kernel<<<8193, 256, 0, stream>>>(x, xs, rowsq);
    lorentz_gemm_kernel<<<BATCH * (NF / MT), 512, 0, stream>>>(xs, wt, rowsq, w0, bv, out);
  } else {
    fallback_kernel<<<BATCH * NF, 256, 0, stream>>>(x, W, bv, out);
  }
}